// Round 1
// baseline (1694.478 us; speedup 1.0000x reference)
//
#include <hip/hip_runtime.h>
#include <hip/hip_bf16.h>
#include <stdint.h>

#define N_USERS 100000
#define N_ITEMS 50000
#define DIM     64
#define QDIM    5
#define NNZ     1000000
#define BATCH   1024
#define HALF_NNZ (NNZ/2)

typedef __hip_bfloat16 bf16;
typedef __attribute__((ext_vector_type(8))) short bf16x8;
typedef __attribute__((ext_vector_type(4))) float f32x4;

// ---------------- threefry2x32 (exact JAX block) ----------------
__host__ __device__ inline void tf2x32(uint32_t k0, uint32_t k1,
                                       uint32_t x0, uint32_t x1,
                                       uint32_t& o0, uint32_t& o1) {
  uint32_t ks2 = k0 ^ k1 ^ 0x1BD11BDAu;
  x0 += k0; x1 += k1;
#define TF_R(r) { x0 += x1; x1 = (x1 << (r)) | (x1 >> (32 - (r))); x1 ^= x0; }
  TF_R(13) TF_R(15) TF_R(26) TF_R(6)
  x0 += k1; x1 += ks2 + 1u;
  TF_R(17) TF_R(29) TF_R(16) TF_R(24)
  x0 += ks2; x1 += k0 + 2u;
  TF_R(13) TF_R(15) TF_R(26) TF_R(6)
  x0 += k0; x1 += k1 + 3u;
  TF_R(17) TF_R(29) TF_R(16) TF_R(24)
  x0 += k1; x1 += ks2 + 4u;
  TF_R(13) TF_R(15) TF_R(26) TF_R(6)
  x0 += ks2; x1 += k0 + 5u;
#undef TF_R
  o0 = x0; o1 = x1;
}

__device__ __forceinline__ float mask_from_bits(uint32_t bits) {
  float f = __uint_as_float((bits >> 9) | 0x3f800000u) - 1.0f;
  return (f < 0.75f) ? (1.0f / 0.75f) : 0.0f;
}

// ---------------- CSR/CSC build ----------------
__global__ __launch_bounds__(256) void k_hist(const int* __restrict__ rows,
                                              const int* __restrict__ cols,
                                              int* __restrict__ cnt_r,
                                              int* __restrict__ cnt_c) {
  int e = blockIdx.x * 256 + threadIdx.x;
  if (e < NNZ) {
    atomicAdd(&cnt_r[rows[e]], 1);
    atomicAdd(&cnt_c[cols[e]], 1);
  }
}

// single block, 1024 threads; cursor may alias cnt
__global__ __launch_bounds__(1024) void k_scan(const int* __restrict__ cnt,
                                               int* __restrict__ ptr,
                                               int* __restrict__ cursor, int n) {
  __shared__ int lds[1024];
  int t = threadIdx.x;
  int chunk = (n + 1023) / 1024;
  int lo = t * chunk, hi = min(lo + chunk, n);
  int s = 0;
  for (int i = lo; i < hi; ++i) s += cnt[i];
  lds[t] = s;
  __syncthreads();
  int v = s;
  for (int off = 1; off < 1024; off <<= 1) {
    int add = (t >= off) ? lds[t - off] : 0;
    __syncthreads();
    lds[t] += add;
    __syncthreads();
  }
  int run = lds[t] - v;   // exclusive prefix of this thread's chunk
  if (t == 1023) ptr[n] = lds[1023];
  for (int i = lo; i < hi; ++i) {
    int c = cnt[i];
    ptr[i] = run;
    cursor[i] = run;
    run += c;
  }
}

__global__ __launch_bounds__(256) void k_scatter(const int* __restrict__ rows,
                                                 const int* __restrict__ cols,
                                                 int* __restrict__ cur_r,
                                                 int* __restrict__ cur_c,
                                                 int* __restrict__ perm_r,
                                                 int* __restrict__ perm_c) {
  int e = blockIdx.x * 256 + threadIdx.x;
  if (e < NNZ) {
    int pr = atomicAdd(&cur_r[rows[e]], 1); perm_r[pr] = e;
    int pc = atomicAdd(&cur_c[cols[e]], 1); perm_c[pc] = e;
  }
}

// ---------------- dropout-masked edge values ----------------
__global__ __launch_bounds__(256) void k_mask_vals(const float* __restrict__ adj_vals,
                                                   float* __restrict__ vu,
                                                   float* __restrict__ vi,
                                                   uint32_t ku0, uint32_t ku1,
                                                   uint32_t ki0, uint32_t ki1) {
  int e = blockIdx.x * 256 + threadIdx.x;
  if (e < HALF_NNZ) {
    float a = adj_vals[e], b = adj_vals[e + HALF_NNZ];
    uint32_t o0, o1;
    tf2x32(ku0, ku1, (uint32_t)e, (uint32_t)(e + HALF_NNZ), o0, o1);
    vu[e] = a * mask_from_bits(o0);
    vu[e + HALF_NNZ] = b * mask_from_bits(o1);
    tf2x32(ki0, ki1, (uint32_t)e, (uint32_t)(e + HALF_NNZ), o0, o1);
    vi[e] = a * mask_from_bits(o0);
    vi[e + HALF_NNZ] = b * mask_from_bits(o1);
  }
}

// ---------------- SpMM: out[r] = sum_{e in r} vals[e] * X[gidx[e]] ----------------
__global__ __launch_bounds__(256) void k_spmm(const int* __restrict__ ptr,
                                              const int* __restrict__ perm,
                                              const float* __restrict__ vals,
                                              const int* __restrict__ gidx,
                                              const float* __restrict__ X,
                                              float* __restrict__ out, int nrows) {
  int w = (blockIdx.x * 256 + threadIdx.x) >> 6;
  int lane = threadIdx.x & 63;
  if (w >= nrows) return;
  int beg = ptr[w], end = ptr[w + 1];
  float acc = 0.f;
  for (int k = beg; k < end; ++k) {
    int e = perm[k];
    acc += vals[e] * X[(size_t)gidx[e] * DIM + lane];
  }
  out[(size_t)w * DIM + lane] = acc;
}

// ---------------- W += Vt(Q x n) @ X(n x 64)  (Q=5, tiny output) ----------------
__global__ __launch_bounds__(256) void k_wred(const float* __restrict__ Vt,
                                              const float* __restrict__ X,
                                              float* __restrict__ W, int n) {
  int lane = threadIdx.x & 63;
  int w = (blockIdx.x * 256 + threadIdx.x) >> 6;
  int nw = (gridDim.x * 256) >> 6;
  float acc[QDIM] = {0.f, 0.f, 0.f, 0.f, 0.f};
  for (int i = w; i < n; i += nw) {
    float x = X[(size_t)i * DIM + lane];
#pragma unroll
    for (int q = 0; q < QDIM; ++q) acc[q] += Vt[(size_t)q * n + i] * x;
  }
#pragma unroll
  for (int q = 0; q < QDIM; ++q) atomicAdd(&W[q * DIM + lane], acc[q]);
}

// ---------------- batch-row prep: sG, sE at batch indices; bf16 G ----------------
__global__ __launch_bounds__(256) void k_prep(const int* __restrict__ uids,
                                              const int* __restrict__ pos,
                                              const int* __restrict__ neg,
                                              const float* __restrict__ Eu0,
                                              const float* __restrict__ Ei0,
                                              const float* __restrict__ umuls,
                                              const float* __restrict__ vmuls,
                                              const float* __restrict__ Zu1,
                                              const float* __restrict__ Zu2,
                                              const float* __restrict__ Zi1,
                                              const float* __restrict__ Zi2,
                                              const float* __restrict__ Wu,
                                              const float* __restrict__ Wi,
                                              float* __restrict__ gu, float* __restrict__ seu,
                                              float* __restrict__ gi, float* __restrict__ sei,
                                              bf16* __restrict__ Gbf) {
  int row = (blockIdx.x * 256 + threadIdx.x) >> 6;
  int lane = threadIdx.x & 63;
  if (row >= 3 * BATCH) return;
  if (row < BATCH) {
    int u = uids[row];
    size_t base = (size_t)u * DIM + lane;
    float e0 = Eu0[base];
    float g = e0;
#pragma unroll
    for (int q = 0; q < QDIM; ++q) g += umuls[u * QDIM + q] * Wu[q * DIM + lane];
    gu[row * DIM + lane] = g;
    Gbf[row * DIM + lane] = __float2bfloat16(g);
    seu[row * DIM + lane] = e0 + Zu1[base] + Zu2[base];
  } else {
    int r = row - BATCH;
    int it = (r < BATCH) ? pos[r] : neg[r - BATCH];
    size_t base = (size_t)it * DIM + lane;
    float e0 = Ei0[base];
    float g = e0;
#pragma unroll
    for (int q = 0; q < QDIM; ++q) g += vmuls[it * QDIM + q] * Wi[q * DIM + lane];
    gi[r * DIM + lane] = g;
    Gbf[row * DIM + lane] = __float2bfloat16(g);
    sei[r * DIM + lane] = e0 + Zi1[base] + Zi2[base];
  }
}

// ---------------- sE = E0 + Z1 + Z2 -> bf16 ----------------
__global__ __launch_bounds__(256) void k_se_bf(const float* __restrict__ E0,
                                               const float* __restrict__ Z1,
                                               const float* __restrict__ Z2,
                                               bf16* __restrict__ out, int n) {
  size_t i = (size_t)blockIdx.x * 256 + threadIdx.x;
  if (i < (size_t)n * DIM) out[i] = __float2bfloat16(E0[i] + Z1[i] + Z2[i]);
}

// ---------------- InfoNCE denominator: S[b] += sum_u exp(dot(G[b],SE[u])/T) ----------------
__global__ __launch_bounds__(256) void k_negsum(const bf16* __restrict__ G,
                                                const bf16* __restrict__ SE,
                                                float* __restrict__ S,
                                                int n, int n_bblk, int uch) {
  int bblk = blockIdx.x % n_bblk;
  int uc = blockIdx.x / n_bblk;
  int wid = threadIdx.x >> 6;
  int lane = threadIdx.x & 63;
  int b0 = bblk * 64 + wid * 16;
  int fr = lane & 15, fq = lane >> 4;

  bf16x8 a0 = *(const bf16x8*)(G + (size_t)(b0 + fr) * DIM + fq * 8);
  bf16x8 a1 = *(const bf16x8*)(G + (size_t)(b0 + fr) * DIM + 32 + fq * 8);

  int tiles = n / 16;
  int per = ((tiles + uch - 1) / uch) * 16;
  int u_lo = uc * per;
  int u_hi = min(n, u_lo + per);

  float racc[4] = {0.f, 0.f, 0.f, 0.f};
  const float invT = 5.0f;   // 1/0.2
  for (int u0 = u_lo; u0 < u_hi; u0 += 16) {
    bf16x8 bfr0 = *(const bf16x8*)(SE + (size_t)(u0 + fr) * DIM + fq * 8);
    bf16x8 bfr1 = *(const bf16x8*)(SE + (size_t)(u0 + fr) * DIM + 32 + fq * 8);
    f32x4 c = {0.f, 0.f, 0.f, 0.f};
    c = __builtin_amdgcn_mfma_f32_16x16x32_bf16(a0, bfr0, c, 0, 0, 0);
    c = __builtin_amdgcn_mfma_f32_16x16x32_bf16(a1, bfr1, c, 0, 0, 0);
#pragma unroll
    for (int j = 0; j < 4; ++j) racc[j] += __expf(c[j] * invT);
  }
#pragma unroll
  for (int j = 0; j < 4; ++j) {
    float v = racc[j];
    v += __shfl_xor(v, 1);
    v += __shfl_xor(v, 2);
    v += __shfl_xor(v, 4);
    v += __shfl_xor(v, 8);
    if (fr == 0) atomicAdd(&S[b0 + fq * 4 + j], v);
  }
}

// ---------------- sum of squares (L2 reg) ----------------
__global__ __launch_bounds__(256) void k_sumsq(const float* __restrict__ X, int n,
                                               float* __restrict__ out) {
  size_t i = (size_t)blockIdx.x * 256 + threadIdx.x;
  size_t stride = (size_t)gridDim.x * 256;
  float s = 0.f;
  for (; i < (size_t)n; i += stride) { float v = X[i]; s += v * v; }
  for (int off = 32; off; off >>= 1) s += __shfl_down(s, off);
  __shared__ float part[4];
  if ((threadIdx.x & 63) == 0) part[threadIdx.x >> 6] = s;
  __syncthreads();
  if (threadIdx.x == 0) atomicAdd(out, part[0] + part[1] + part[2] + part[3]);
}

// ---------------- final scalar assembly ----------------
__global__ __launch_bounds__(256) void k_final(const float* __restrict__ Su,
                                               const float* __restrict__ Si,
                                               const float* __restrict__ gu,
                                               const float* __restrict__ seu,
                                               const float* __restrict__ gi,
                                               const float* __restrict__ sei,
                                               const float* __restrict__ sumsq,
                                               float* __restrict__ out) {
  int t = threadIdx.x;
  float negu = 0.f, negi = 0.f, posu = 0.f, posi = 0.f, bpr = 0.f;
  const float invT = 5.0f;
  for (int b = t; b < BATCH; b += 256) {
    negu += logf(Su[b] + 1e-8f);
    float d = 0.f, dp = 0.f, dn = 0.f;
    for (int q = 0; q < DIM; ++q) {
      float u = seu[b * DIM + q];
      d += gu[b * DIM + q] * u;
      dp += u * sei[b * DIM + q];
      dn += u * sei[(b + BATCH) * DIM + q];
    }
    posu += fminf(fmaxf(d * invT, -5.f), 5.f);
    float diff = dp - dn;
    bpr += fmaxf(-diff, 0.f) + log1pf(expf(-fabsf(diff)));
  }
  for (int b = t; b < 2 * BATCH; b += 256) {
    negi += logf(Si[b] + 1e-8f);
    float d = 0.f;
    for (int q = 0; q < DIM; ++q) d += gi[b * DIM + q] * sei[b * DIM + q];
    posi += fminf(fmaxf(d * invT, -5.f), 5.f);
  }
  __shared__ float red[5][4];
  float vals5[5] = {negu, negi, posu, posi, bpr};
#pragma unroll
  for (int k = 0; k < 5; ++k) {
    float v = vals5[k];
    for (int off = 32; off; off >>= 1) v += __shfl_down(v, off);
    if ((t & 63) == 0) red[k][t >> 6] = v;
  }
  __syncthreads();
  if (t == 0) {
    float nu = red[0][0] + red[0][1] + red[0][2] + red[0][3];
    float ni = red[1][0] + red[1][1] + red[1][2] + red[1][3];
    float pu = red[2][0] + red[2][1] + red[2][2] + red[2][3];
    float pi = red[3][0] + red[3][1] + red[3][2] + red[3][3];
    float bp = red[4][0] + red[4][1] + red[4][2] + red[4][3];
    float neg_score = nu / (float)BATCH + ni / (float)(2 * BATCH);
    float pos_score = pu / (float)BATCH + pi / (float)(2 * BATCH);
    float loss_s = -pos_score + neg_score;
    float loss_r = bp / (float)BATCH;
    float ls = 0.2f * loss_s;
    float reg = 1e-5f * sumsq[0];
    out[0] = loss_r + ls + reg;
    out[1] = loss_r;
    out[2] = ls;
  }
}

extern "C" void kernel_launch(void* const* d_in, const int* in_sizes, int n_in,
                              void* d_out, int out_size, void* d_ws, size_t ws_size,
                              hipStream_t stream) {
  const float* Eu0   = (const float*)d_in[0];
  const float* Ei0   = (const float*)d_in[1];
  const float* umuls = (const float*)d_in[2];
  const float* vmuls = (const float*)d_in[3];
  const float* ut    = (const float*)d_in[4];
  const float* vt    = (const float*)d_in[5];
  const float* adj_vals = (const float*)d_in[6];
  const int* adj_rows = (const int*)d_in[7];
  const int* adj_cols = (const int*)d_in[8];
  const int* uids = (const int*)d_in[9];
  const int* pos  = (const int*)d_in[10];
  const int* neg  = (const int*)d_in[11];
  float* out = (float*)d_out;

  char* w = (char*)d_ws;
  size_t off = 0;
  auto alloc = [&](size_t bytes) -> void* {
    void* p = w + off;
    off = (off + bytes + 255) & ~(size_t)255;
    return p;
  };
  float* Zu1 = (float*)alloc(sizeof(float) * N_USERS * DIM);
  float* Zu2 = (float*)alloc(sizeof(float) * N_USERS * DIM);
  float* Zi1 = (float*)alloc(sizeof(float) * N_ITEMS * DIM);
  float* Zi2 = (float*)alloc(sizeof(float) * N_ITEMS * DIM);
  int* perm_r = (int*)alloc(sizeof(int) * NNZ);
  int* perm_c = (int*)alloc(sizeof(int) * NNZ);
  int* row_ptr = (int*)alloc(sizeof(int) * (N_USERS + 1));
  int* col_ptr = (int*)alloc(sizeof(int) * (N_ITEMS + 1));
  int* cur_r = (int*)alloc(sizeof(int) * N_USERS);
  int* cur_c = (int*)alloc(sizeof(int) * N_ITEMS);
  float* vu = (float*)alloc(sizeof(float) * NNZ);
  float* vi = (float*)alloc(sizeof(float) * NNZ);
  float* Wu = (float*)alloc(sizeof(float) * QDIM * DIM);
  float* Wi = (float*)alloc(sizeof(float) * QDIM * DIM);
  float* gu  = (float*)alloc(sizeof(float) * BATCH * DIM);
  float* gi  = (float*)alloc(sizeof(float) * 2 * BATCH * DIM);
  float* seu = (float*)alloc(sizeof(float) * BATCH * DIM);
  float* sei = (float*)alloc(sizeof(float) * 2 * BATCH * DIM);
  bf16* sEu_bf = (bf16*)alloc(sizeof(bf16) * N_USERS * DIM);
  bf16* sEi_bf = (bf16*)alloc(sizeof(bf16) * N_ITEMS * DIM);
  bf16* Gbf = (bf16*)alloc(sizeof(bf16) * 3 * BATCH * DIM);
  float* Su = (float*)alloc(sizeof(float) * BATCH);
  float* Si = (float*)alloc(sizeof(float) * 2 * BATCH);
  float* scal = (float*)alloc(sizeof(float) * 4);

  // folded dropout keys: fold_in(key(42), idx) for idx = 0..3
  uint32_t mk[4][2];
  for (uint32_t i = 0; i < 4; ++i) tf2x32(0u, 42u, 0u, i, mk[i][0], mk[i][1]);

  hipMemsetAsync(cur_r, 0, sizeof(int) * N_USERS, stream);
  hipMemsetAsync(cur_c, 0, sizeof(int) * N_ITEMS, stream);
  hipMemsetAsync(Wu, 0, sizeof(float) * QDIM * DIM, stream);
  hipMemsetAsync(Wi, 0, sizeof(float) * QDIM * DIM, stream);
  hipMemsetAsync(Su, 0, sizeof(float) * BATCH, stream);
  hipMemsetAsync(Si, 0, sizeof(float) * 2 * BATCH, stream);
  hipMemsetAsync(scal, 0, sizeof(float) * 4, stream);

  // CSR/CSC build
  k_hist<<<(NNZ + 255) / 256, 256, 0, stream>>>(adj_rows, adj_cols, cur_r, cur_c);
  k_scan<<<1, 1024, 0, stream>>>(cur_r, row_ptr, cur_r, N_USERS);
  k_scan<<<1, 1024, 0, stream>>>(cur_c, col_ptr, cur_c, N_ITEMS);
  k_scatter<<<(NNZ + 255) / 256, 256, 0, stream>>>(adj_rows, adj_cols, cur_r, cur_c, perm_r, perm_c);

  // layer 0
  k_mask_vals<<<(HALF_NNZ + 255) / 256, 256, 0, stream>>>(adj_vals, vu, vi,
                                                          mk[0][0], mk[0][1], mk[1][0], mk[1][1]);
  k_spmm<<<N_USERS * 64 / 256, 256, 0, stream>>>(row_ptr, perm_r, vu, adj_cols, Ei0, Zu1, N_USERS);
  k_spmm<<<N_ITEMS * 64 / 256, 256, 0, stream>>>(col_ptr, perm_c, vi, adj_rows, Eu0, Zi1, N_ITEMS);
  k_wred<<<256, 256, 0, stream>>>(vt, Ei0, Wu, N_ITEMS);
  k_wred<<<256, 256, 0, stream>>>(ut, Eu0, Wi, N_USERS);

  // layer 1
  k_mask_vals<<<(HALF_NNZ + 255) / 256, 256, 0, stream>>>(adj_vals, vu, vi,
                                                          mk[2][0], mk[2][1], mk[3][0], mk[3][1]);
  k_spmm<<<N_USERS * 64 / 256, 256, 0, stream>>>(row_ptr, perm_r, vu, adj_cols, Zi1, Zu2, N_USERS);
  k_spmm<<<N_ITEMS * 64 / 256, 256, 0, stream>>>(col_ptr, perm_c, vi, adj_rows, Zu1, Zi2, N_ITEMS);
  k_wred<<<256, 256, 0, stream>>>(vt, Zi1, Wu, N_ITEMS);
  k_wred<<<256, 256, 0, stream>>>(ut, Zu1, Wi, N_USERS);

  // batch prep + bf16 tables
  k_prep<<<(3 * BATCH * 64) / 256, 256, 0, stream>>>(uids, pos, neg, Eu0, Ei0, umuls, vmuls,
                                                     Zu1, Zu2, Zi1, Zi2, Wu, Wi,
                                                     gu, seu, gi, sei, Gbf);
  k_se_bf<<<(N_USERS * DIM + 255) / 256, 256, 0, stream>>>(Eu0, Zu1, Zu2, sEu_bf, N_USERS);
  k_se_bf<<<(N_ITEMS * DIM + 255) / 256, 256, 0, stream>>>(Ei0, Zi1, Zi2, sEi_bf, N_ITEMS);

  // InfoNCE denominators (MFMA)
  k_negsum<<<16 * 32, 256, 0, stream>>>(Gbf, sEu_bf, Su, N_USERS, 16, 32);
  k_negsum<<<32 * 32, 256, 0, stream>>>(Gbf + (size_t)BATCH * DIM, sEi_bf, Si, N_ITEMS, 32, 32);

  // L2 reg
  k_sumsq<<<2048, 256, 0, stream>>>(Eu0, N_USERS * DIM, scal);
  k_sumsq<<<1024, 256, 0, stream>>>(Ei0, N_ITEMS * DIM, scal);

  // final scalars
  k_final<<<1, 256, 0, stream>>>(Su, Si, gu, seu, gi, sei, scal, out);
}

// Round 2
// 1023.159 us; speedup vs baseline: 1.6561x; 1.6561x over previous
//
#include <hip/hip_runtime.h>
#include <hip/hip_bf16.h>
#include <stdint.h>

#define N_USERS 100000
#define N_ITEMS 50000
#define DIM     64
#define QDIM    5
#define NNZ     1000000
#define BATCH   1024
#define HALF_NNZ (NNZ/2)
#define SC_E    2048   // elements per scan block (256 thr x 8)

typedef __hip_bfloat16 bf16;
typedef __attribute__((ext_vector_type(8))) short bf16x8;
typedef __attribute__((ext_vector_type(4))) float f32x4;

// ---------------- threefry2x32 (exact JAX block) ----------------
__host__ __device__ inline void tf2x32(uint32_t k0, uint32_t k1,
                                       uint32_t x0, uint32_t x1,
                                       uint32_t& o0, uint32_t& o1) {
  uint32_t ks2 = k0 ^ k1 ^ 0x1BD11BDAu;
  x0 += k0; x1 += k1;
#define TF_R(r) { x0 += x1; x1 = (x1 << (r)) | (x1 >> (32 - (r))); x1 ^= x0; }
  TF_R(13) TF_R(15) TF_R(26) TF_R(6)
  x0 += k1; x1 += ks2 + 1u;
  TF_R(17) TF_R(29) TF_R(16) TF_R(24)
  x0 += ks2; x1 += k0 + 2u;
  TF_R(13) TF_R(15) TF_R(26) TF_R(6)
  x0 += k0; x1 += k1 + 3u;
  TF_R(17) TF_R(29) TF_R(16) TF_R(24)
  x0 += k1; x1 += ks2 + 4u;
  TF_R(13) TF_R(15) TF_R(26) TF_R(6)
  x0 += ks2; x1 += k0 + 5u;
#undef TF_R
  o0 = x0; o1 = x1;
}

__device__ __forceinline__ float mask_from_bits(uint32_t bits) {
  float f = __uint_as_float((bits >> 9) | 0x3f800000u) - 1.0f;
  return (f < 0.75f) ? (1.0f / 0.75f) : 0.0f;
}

// ---------------- CSR/CSC build ----------------
__global__ __launch_bounds__(256) void k_hist(const int* __restrict__ rows,
                                              const int* __restrict__ cols,
                                              int* __restrict__ cnt_r,
                                              int* __restrict__ cnt_c) {
  int e = blockIdx.x * 256 + threadIdx.x;
  if (e < NNZ) {
    atomicAdd(&cnt_r[rows[e]], 1);
    atomicAdd(&cnt_c[cols[e]], 1);
  }
}

// phase 1: per-block sums (block b covers [b*SC_E, b*SC_E+SC_E))
__global__ __launch_bounds__(256) void k_bsum(const int* __restrict__ cnt, int n,
                                              int* __restrict__ bsum) {
  int base = blockIdx.x * SC_E + threadIdx.x * 8;
  int s = 0;
#pragma unroll
  for (int j = 0; j < 8; ++j) { int i = base + j; if (i < n) s += cnt[i]; }
  for (int off = 32; off; off >>= 1) s += __shfl_down(s, off);
  __shared__ int ws[4];
  if ((threadIdx.x & 63) == 0) ws[threadIdx.x >> 6] = s;
  __syncthreads();
  if (threadIdx.x == 0) bsum[blockIdx.x] = ws[0] + ws[1] + ws[2] + ws[3];
}

// phase 2: one wave scans <=64 block sums; writes exclusive block offsets + total
__global__ __launch_bounds__(64) void k_bscan(const int* __restrict__ bsum, int nb,
                                              int* __restrict__ boff,
                                              int* __restrict__ total_dst) {
  int lane = threadIdx.x;
  int v = (lane < nb) ? bsum[lane] : 0;
  int incl = v;
  for (int off = 1; off < 64; off <<= 1) {
    int t = __shfl_up(incl, off);
    if (lane >= off) incl += t;
  }
  if (lane < nb) boff[lane] = incl - v;
  if (lane == 63) *total_dst = incl;
}

// phase 3: per-block exclusive scan; writes ptr[i] and cursor[i]
// NOTE: cnt and cursor may alias (reads complete before writes per thread).
__global__ __launch_bounds__(256) void k_scan3(const int* cnt, int n,
                                               const int* __restrict__ boff,
                                               int* __restrict__ ptr, int* cursor) {
  int base = blockIdx.x * SC_E + threadIdx.x * 8;
  int c[8]; int s = 0;
#pragma unroll
  for (int j = 0; j < 8; ++j) { int i = base + j; c[j] = (i < n) ? cnt[i] : 0; s += c[j]; }
  int lane = threadIdx.x & 63, wid = threadIdx.x >> 6;
  int incl = s;
  for (int off = 1; off < 64; off <<= 1) {
    int t = __shfl_up(incl, off);
    if (lane >= off) incl += t;
  }
  __shared__ int wsum[4];
  if (lane == 63) wsum[wid] = incl;
  __syncthreads();
  int wpre = 0;
  for (int k = 0; k < wid; ++k) wpre += wsum[k];
  int run = boff[blockIdx.x] + wpre + (incl - s);
#pragma unroll
  for (int j = 0; j < 8; ++j) {
    int i = base + j;
    if (i < n) { ptr[i] = run; cursor[i] = run; run += c[j]; }
  }
}

// scatter: build CSR/CSC with values + column/row indices in permuted order
__global__ __launch_bounds__(256) void k_scatter(const int* __restrict__ rows,
                                                 const int* __restrict__ cols,
                                                 const float* __restrict__ adj_vals,
                                                 int* __restrict__ cur_r,
                                                 int* __restrict__ cur_c,
                                                 int* __restrict__ perm_r,
                                                 int* __restrict__ perm_c,
                                                 int* __restrict__ csr_col,
                                                 int* __restrict__ csc_row,
                                                 float* __restrict__ av_r,
                                                 float* __restrict__ av_c) {
  int e = blockIdx.x * 256 + threadIdx.x;
  if (e < NNZ) {
    int r = rows[e], c = cols[e];
    float v = adj_vals[e];
    int pr = atomicAdd(&cur_r[r], 1);
    perm_r[pr] = e; csr_col[pr] = c; av_r[pr] = v;
    int pc = atomicAdd(&cur_c[c], 1);
    perm_c[pc] = e; csc_row[pc] = r; av_c[pc] = v;
  }
}

// masked values in CSR order: vout[k] = av[k] * mask(perm[k])
__global__ __launch_bounds__(256) void k_mask_csr(const int* __restrict__ perm,
                                                  const float* __restrict__ av,
                                                  float* __restrict__ vout,
                                                  uint32_t k0, uint32_t k1) {
  int k = blockIdx.x * 256 + threadIdx.x;
  if (k < NNZ) {
    int e = perm[k];
    uint32_t x0 = (e < HALF_NNZ) ? (uint32_t)e : (uint32_t)(e - HALF_NNZ);
    uint32_t o0, o1;
    tf2x32(k0, k1, x0, x0 + HALF_NNZ, o0, o1);
    uint32_t bits = (e < HALF_NNZ) ? o0 : o1;
    vout[k] = av[k] * mask_from_bits(bits);
  }
}

// ---------------- SpMM: out[r] = sum_{k in row r} vals[k] * X[cidx[k]] ----------------
__global__ __launch_bounds__(256) void k_spmm(const int* __restrict__ ptr,
                                              const int* __restrict__ cidx,
                                              const float* __restrict__ vals,
                                              const float* __restrict__ X,
                                              float* __restrict__ out, int nrows) {
  int w = (blockIdx.x * 256 + threadIdx.x) >> 6;
  int lane = threadIdx.x & 63;
  if (w >= nrows) return;
  int beg = ptr[w], end = ptr[w + 1];
  float acc = 0.f;
  for (int k0 = beg; k0 < end; k0 += 64) {
    int cnt = min(64, end - k0);
    float v = (lane < cnt) ? vals[k0 + lane] : 0.f;
    int   c = (lane < cnt) ? cidx[k0 + lane] : 0;
    for (int j = 0; j < cnt; ++j) {
      float vj = __shfl(v, j);
      int   cj = __shfl(c, j);
      acc += vj * X[(size_t)cj * DIM + lane];
    }
  }
  out[(size_t)w * DIM + lane] = acc;
}

// ---------------- W += Vt(Q x n) @ X(n x 64)  (Q=5, tiny output) ----------------
__global__ __launch_bounds__(256) void k_wred(const float* __restrict__ Vt,
                                              const float* __restrict__ X,
                                              float* __restrict__ W, int n) {
  int lane = threadIdx.x & 63;
  int w = (blockIdx.x * 256 + threadIdx.x) >> 6;
  int nw = (gridDim.x * 256) >> 6;
  float acc[QDIM] = {0.f, 0.f, 0.f, 0.f, 0.f};
  for (int i = w; i < n; i += nw) {
    float x = X[(size_t)i * DIM + lane];
#pragma unroll
    for (int q = 0; q < QDIM; ++q) acc[q] += Vt[(size_t)q * n + i] * x;
  }
#pragma unroll
  for (int q = 0; q < QDIM; ++q) atomicAdd(&W[q * DIM + lane], acc[q]);
}

// ---------------- batch-row prep: sG, sE at batch indices; bf16 G ----------------
__global__ __launch_bounds__(256) void k_prep(const int* __restrict__ uids,
                                              const int* __restrict__ pos,
                                              const int* __restrict__ neg,
                                              const float* __restrict__ Eu0,
                                              const float* __restrict__ Ei0,
                                              const float* __restrict__ umuls,
                                              const float* __restrict__ vmuls,
                                              const float* __restrict__ Zu1,
                                              const float* __restrict__ Zu2,
                                              const float* __restrict__ Zi1,
                                              const float* __restrict__ Zi2,
                                              const float* __restrict__ Wu,
                                              const float* __restrict__ Wi,
                                              float* __restrict__ gu, float* __restrict__ seu,
                                              float* __restrict__ gi, float* __restrict__ sei,
                                              bf16* __restrict__ Gbf) {
  int row = (blockIdx.x * 256 + threadIdx.x) >> 6;
  int lane = threadIdx.x & 63;
  if (row >= 3 * BATCH) return;
  if (row < BATCH) {
    int u = uids[row];
    size_t base = (size_t)u * DIM + lane;
    float e0 = Eu0[base];
    float g = e0;
#pragma unroll
    for (int q = 0; q < QDIM; ++q) g += umuls[u * QDIM + q] * Wu[q * DIM + lane];
    gu[row * DIM + lane] = g;
    Gbf[row * DIM + lane] = __float2bfloat16(g);
    seu[row * DIM + lane] = e0 + Zu1[base] + Zu2[base];
  } else {
    int r = row - BATCH;
    int it = (r < BATCH) ? pos[r] : neg[r - BATCH];
    size_t base = (size_t)it * DIM + lane;
    float e0 = Ei0[base];
    float g = e0;
#pragma unroll
    for (int q = 0; q < QDIM; ++q) g += vmuls[it * QDIM + q] * Wi[q * DIM + lane];
    gi[r * DIM + lane] = g;
    Gbf[row * DIM + lane] = __float2bfloat16(g);
    sei[r * DIM + lane] = e0 + Zi1[base] + Zi2[base];
  }
}

// ---------------- sE = E0 + Z1 + Z2 -> bf16 ----------------
__global__ __launch_bounds__(256) void k_se_bf(const float* __restrict__ E0,
                                               const float* __restrict__ Z1,
                                               const float* __restrict__ Z2,
                                               bf16* __restrict__ out, int n) {
  size_t i = (size_t)blockIdx.x * 256 + threadIdx.x;
  if (i < (size_t)n * DIM) out[i] = __float2bfloat16(E0[i] + Z1[i] + Z2[i]);
}

// ---------------- InfoNCE denominator: S[b] += sum_u exp(dot(G[b],SE[u])/T) ----------------
__global__ __launch_bounds__(256) void k_negsum(const bf16* __restrict__ G,
                                                const bf16* __restrict__ SE,
                                                float* __restrict__ S,
                                                int n, int n_bblk, int uch) {
  int bblk = blockIdx.x % n_bblk;
  int uc = blockIdx.x / n_bblk;
  int wid = threadIdx.x >> 6;
  int lane = threadIdx.x & 63;
  int b0 = bblk * 64 + wid * 16;
  int fr = lane & 15, fq = lane >> 4;

  bf16x8 a0 = *(const bf16x8*)(G + (size_t)(b0 + fr) * DIM + fq * 8);
  bf16x8 a1 = *(const bf16x8*)(G + (size_t)(b0 + fr) * DIM + 32 + fq * 8);

  int tiles = n / 16;
  int per = ((tiles + uch - 1) / uch) * 16;
  int u_lo = uc * per;
  int u_hi = min(n, u_lo + per);

  float racc[4] = {0.f, 0.f, 0.f, 0.f};
  const float invT = 5.0f;   // 1/0.2
  for (int u0 = u_lo; u0 < u_hi; u0 += 16) {
    bf16x8 bfr0 = *(const bf16x8*)(SE + (size_t)(u0 + fr) * DIM + fq * 8);
    bf16x8 bfr1 = *(const bf16x8*)(SE + (size_t)(u0 + fr) * DIM + 32 + fq * 8);
    f32x4 c = {0.f, 0.f, 0.f, 0.f};
    c = __builtin_amdgcn_mfma_f32_16x16x32_bf16(a0, bfr0, c, 0, 0, 0);
    c = __builtin_amdgcn_mfma_f32_16x16x32_bf16(a1, bfr1, c, 0, 0, 0);
#pragma unroll
    for (int j = 0; j < 4; ++j) racc[j] += __expf(c[j] * invT);
  }
#pragma unroll
  for (int j = 0; j < 4; ++j) {
    float v = racc[j];
    v += __shfl_xor(v, 1);
    v += __shfl_xor(v, 2);
    v += __shfl_xor(v, 4);
    v += __shfl_xor(v, 8);
    if (fr == 0) atomicAdd(&S[b0 + fq * 4 + j], v);
  }
}

// ---------------- sum of squares (L2 reg) ----------------
__global__ __launch_bounds__(256) void k_sumsq(const float* __restrict__ X, int n,
                                               float* __restrict__ out) {
  size_t i = (size_t)blockIdx.x * 256 + threadIdx.x;
  size_t stride = (size_t)gridDim.x * 256;
  float s = 0.f;
  for (; i < (size_t)n; i += stride) { float v = X[i]; s += v * v; }
  for (int off = 32; off; off >>= 1) s += __shfl_down(s, off);
  __shared__ float part[4];
  if ((threadIdx.x & 63) == 0) part[threadIdx.x >> 6] = s;
  __syncthreads();
  if (threadIdx.x == 0) atomicAdd(out, part[0] + part[1] + part[2] + part[3]);
}

// ---------------- final scalar assembly ----------------
__global__ __launch_bounds__(256) void k_final(const float* __restrict__ Su,
                                               const float* __restrict__ Si,
                                               const float* __restrict__ gu,
                                               const float* __restrict__ seu,
                                               const float* __restrict__ gi,
                                               const float* __restrict__ sei,
                                               const float* __restrict__ sumsq,
                                               float* __restrict__ out) {
  int t = threadIdx.x;
  float negu = 0.f, negi = 0.f, posu = 0.f, posi = 0.f, bpr = 0.f;
  const float invT = 5.0f;
  for (int b = t; b < BATCH; b += 256) {
    negu += logf(Su[b] + 1e-8f);
    float d = 0.f, dp = 0.f, dn = 0.f;
    for (int q = 0; q < DIM; ++q) {
      float u = seu[b * DIM + q];
      d += gu[b * DIM + q] * u;
      dp += u * sei[b * DIM + q];
      dn += u * sei[(b + BATCH) * DIM + q];
    }
    posu += fminf(fmaxf(d * invT, -5.f), 5.f);
    float diff = dp - dn;
    bpr += fmaxf(-diff, 0.f) + log1pf(expf(-fabsf(diff)));
  }
  for (int b = t; b < 2 * BATCH; b += 256) {
    negi += logf(Si[b] + 1e-8f);
    float d = 0.f;
    for (int q = 0; q < DIM; ++q) d += gi[b * DIM + q] * sei[b * DIM + q];
    posi += fminf(fmaxf(d * invT, -5.f), 5.f);
  }
  __shared__ float red[5][4];
  float vals5[5] = {negu, negi, posu, posi, bpr};
#pragma unroll
  for (int k = 0; k < 5; ++k) {
    float v = vals5[k];
    for (int off = 32; off; off >>= 1) v += __shfl_down(v, off);
    if ((t & 63) == 0) red[k][t >> 6] = v;
  }
  __syncthreads();
  if (t == 0) {
    float nu = red[0][0] + red[0][1] + red[0][2] + red[0][3];
    float ni = red[1][0] + red[1][1] + red[1][2] + red[1][3];
    float pu = red[2][0] + red[2][1] + red[2][2] + red[2][3];
    float pi = red[3][0] + red[3][1] + red[3][2] + red[3][3];
    float bp = red[4][0] + red[4][1] + red[4][2] + red[4][3];
    float neg_score = nu / (float)BATCH + ni / (float)(2 * BATCH);
    float pos_score = pu / (float)BATCH + pi / (float)(2 * BATCH);
    float loss_s = -pos_score + neg_score;
    float loss_r = bp / (float)BATCH;
    float ls = 0.2f * loss_s;
    float reg = 1e-5f * sumsq[0];
    out[0] = loss_r + ls + reg;
    out[1] = loss_r;
    out[2] = ls;
  }
}

extern "C" void kernel_launch(void* const* d_in, const int* in_sizes, int n_in,
                              void* d_out, int out_size, void* d_ws, size_t ws_size,
                              hipStream_t stream) {
  const float* Eu0   = (const float*)d_in[0];
  const float* Ei0   = (const float*)d_in[1];
  const float* umuls = (const float*)d_in[2];
  const float* vmuls = (const float*)d_in[3];
  const float* ut    = (const float*)d_in[4];
  const float* vt    = (const float*)d_in[5];
  const float* adj_vals = (const float*)d_in[6];
  const int* adj_rows = (const int*)d_in[7];
  const int* adj_cols = (const int*)d_in[8];
  const int* uids = (const int*)d_in[9];
  const int* pos  = (const int*)d_in[10];
  const int* neg  = (const int*)d_in[11];
  float* out = (float*)d_out;

  char* w = (char*)d_ws;
  size_t off = 0;
  auto alloc = [&](size_t bytes) -> void* {
    void* p = w + off;
    off = (off + bytes + 255) & ~(size_t)255;
    return p;
  };
  float* Zu1 = (float*)alloc(sizeof(float) * N_USERS * DIM);
  float* Zu2 = (float*)alloc(sizeof(float) * N_USERS * DIM);
  float* Zi1 = (float*)alloc(sizeof(float) * N_ITEMS * DIM);
  float* Zi2 = (float*)alloc(sizeof(float) * N_ITEMS * DIM);
  int* perm_r = (int*)alloc(sizeof(int) * NNZ);
  int* perm_c = (int*)alloc(sizeof(int) * NNZ);
  int* csr_col = (int*)alloc(sizeof(int) * NNZ);
  int* csc_row = (int*)alloc(sizeof(int) * NNZ);
  float* av_r = (float*)alloc(sizeof(float) * NNZ);
  float* av_c = (float*)alloc(sizeof(float) * NNZ);
  int* row_ptr = (int*)alloc(sizeof(int) * (N_USERS + 1));
  int* col_ptr = (int*)alloc(sizeof(int) * (N_ITEMS + 1));
  int* cur_r = (int*)alloc(sizeof(int) * N_USERS);
  int* cur_c = (int*)alloc(sizeof(int) * N_ITEMS);
  int* bsum = (int*)alloc(sizeof(int) * 64);
  int* boff = (int*)alloc(sizeof(int) * 64);
  int* bsum2 = (int*)alloc(sizeof(int) * 64);
  int* boff2 = (int*)alloc(sizeof(int) * 64);
  float* vu = (float*)alloc(sizeof(float) * NNZ);
  float* vi = (float*)alloc(sizeof(float) * NNZ);
  float* Wu = (float*)alloc(sizeof(float) * QDIM * DIM);
  float* Wi = (float*)alloc(sizeof(float) * QDIM * DIM);
  float* gu  = (float*)alloc(sizeof(float) * BATCH * DIM);
  float* gi  = (float*)alloc(sizeof(float) * 2 * BATCH * DIM);
  float* seu = (float*)alloc(sizeof(float) * BATCH * DIM);
  float* sei = (float*)alloc(sizeof(float) * 2 * BATCH * DIM);
  bf16* sEu_bf = (bf16*)alloc(sizeof(bf16) * N_USERS * DIM);
  bf16* sEi_bf = (bf16*)alloc(sizeof(bf16) * N_ITEMS * DIM);
  bf16* Gbf = (bf16*)alloc(sizeof(bf16) * 3 * BATCH * DIM);
  float* Su = (float*)alloc(sizeof(float) * BATCH);
  float* Si = (float*)alloc(sizeof(float) * 2 * BATCH);
  float* scal = (float*)alloc(sizeof(float) * 4);

  // folded dropout keys: fold_in(key(42), idx) for idx = 0..3
  uint32_t mk[4][2];
  for (uint32_t i = 0; i < 4; ++i) tf2x32(0u, 42u, 0u, i, mk[i][0], mk[i][1]);

  const int NB_U = (N_USERS + SC_E - 1) / SC_E;   // 49
  const int NB_I = (N_ITEMS + SC_E - 1) / SC_E;   // 25

  hipMemsetAsync(cur_r, 0, sizeof(int) * N_USERS, stream);
  hipMemsetAsync(cur_c, 0, sizeof(int) * N_ITEMS, stream);
  hipMemsetAsync(Wu, 0, sizeof(float) * QDIM * DIM, stream);
  hipMemsetAsync(Wi, 0, sizeof(float) * QDIM * DIM, stream);
  hipMemsetAsync(Su, 0, sizeof(float) * BATCH, stream);
  hipMemsetAsync(Si, 0, sizeof(float) * 2 * BATCH, stream);
  hipMemsetAsync(scal, 0, sizeof(float) * 4, stream);

  // CSR/CSC build
  k_hist<<<(NNZ + 255) / 256, 256, 0, stream>>>(adj_rows, adj_cols, cur_r, cur_c);
  // hierarchical exclusive scans (users, items)
  k_bsum<<<NB_U, 256, 0, stream>>>(cur_r, N_USERS, bsum);
  k_bscan<<<1, 64, 0, stream>>>(bsum, NB_U, boff, row_ptr + N_USERS);
  k_scan3<<<NB_U, 256, 0, stream>>>(cur_r, N_USERS, boff, row_ptr, cur_r);
  k_bsum<<<NB_I, 256, 0, stream>>>(cur_c, N_ITEMS, bsum2);
  k_bscan<<<1, 64, 0, stream>>>(bsum2, NB_I, boff2, col_ptr + N_ITEMS);
  k_scan3<<<NB_I, 256, 0, stream>>>(cur_c, N_ITEMS, boff2, col_ptr, cur_c);
  k_scatter<<<(NNZ + 255) / 256, 256, 0, stream>>>(adj_rows, adj_cols, adj_vals,
                                                   cur_r, cur_c, perm_r, perm_c,
                                                   csr_col, csc_row, av_r, av_c);

  // layer 0: masked values in CSR/CSC order, then SpMM + SVD reductions
  k_mask_csr<<<(NNZ + 255) / 256, 256, 0, stream>>>(perm_r, av_r, vu, mk[0][0], mk[0][1]);
  k_mask_csr<<<(NNZ + 255) / 256, 256, 0, stream>>>(perm_c, av_c, vi, mk[1][0], mk[1][1]);
  k_spmm<<<N_USERS * 64 / 256, 256, 0, stream>>>(row_ptr, csr_col, vu, Ei0, Zu1, N_USERS);
  k_spmm<<<N_ITEMS * 64 / 256, 256, 0, stream>>>(col_ptr, csc_row, vi, Eu0, Zi1, N_ITEMS);
  k_wred<<<256, 256, 0, stream>>>(vt, Ei0, Wu, N_ITEMS);
  k_wred<<<256, 256, 0, stream>>>(ut, Eu0, Wi, N_USERS);

  // layer 1
  k_mask_csr<<<(NNZ + 255) / 256, 256, 0, stream>>>(perm_r, av_r, vu, mk[2][0], mk[2][1]);
  k_mask_csr<<<(NNZ + 255) / 256, 256, 0, stream>>>(perm_c, av_c, vi, mk[3][0], mk[3][1]);
  k_spmm<<<N_USERS * 64 / 256, 256, 0, stream>>>(row_ptr, csr_col, vu, Zi1, Zu2, N_USERS);
  k_spmm<<<N_ITEMS * 64 / 256, 256, 0, stream>>>(col_ptr, csc_row, vi, Zu1, Zi2, N_ITEMS);
  k_wred<<<256, 256, 0, stream>>>(vt, Zi1, Wu, N_ITEMS);
  k_wred<<<256, 256, 0, stream>>>(ut, Zu1, Wi, N_USERS);

  // batch prep + bf16 tables
  k_prep<<<(3 * BATCH * 64) / 256, 256, 0, stream>>>(uids, pos, neg, Eu0, Ei0, umuls, vmuls,
                                                     Zu1, Zu2, Zi1, Zi2, Wu, Wi,
                                                     gu, seu, gi, sei, Gbf);
  k_se_bf<<<(N_USERS * DIM + 255) / 256, 256, 0, stream>>>(Eu0, Zu1, Zu2, sEu_bf, N_USERS);
  k_se_bf<<<(N_ITEMS * DIM + 255) / 256, 256, 0, stream>>>(Ei0, Zi1, Zi2, sEi_bf, N_ITEMS);

  // InfoNCE denominators (MFMA)
  k_negsum<<<16 * 32, 256, 0, stream>>>(Gbf, sEu_bf, Su, N_USERS, 16, 32);
  k_negsum<<<32 * 32, 256, 0, stream>>>(Gbf + (size_t)BATCH * DIM, sEi_bf, Si, N_ITEMS, 32, 32);

  // L2 reg
  k_sumsq<<<2048, 256, 0, stream>>>(Eu0, N_USERS * DIM, scal);
  k_sumsq<<<1024, 256, 0, stream>>>(Ei0, N_ITEMS * DIM, scal);

  // final scalars
  k_final<<<1, 256, 0, stream>>>(Su, Si, gu, seu, gi, sei, scal, out);
}

// Round 3
// 1001.769 us; speedup vs baseline: 1.6915x; 1.0214x over previous
//
#include <hip/hip_runtime.h>
#include <hip/hip_bf16.h>
#include <stdint.h>

#define N_USERS 100000
#define N_ITEMS 50000
#define DIM     64
#define QDIM    5
#define NNZ     1000000
#define BATCH   1024
#define HALF_NNZ (NNZ/2)
#define SC_E    2048   // elements per scan block (256 thr x 8)

typedef __hip_bfloat16 bf16;
typedef __attribute__((ext_vector_type(8))) short bf16x8;
typedef __attribute__((ext_vector_type(4))) float f32x4;

// ---------------- threefry2x32 (exact JAX block) ----------------
__host__ __device__ inline void tf2x32(uint32_t k0, uint32_t k1,
                                       uint32_t x0, uint32_t x1,
                                       uint32_t& o0, uint32_t& o1) {
  uint32_t ks2 = k0 ^ k1 ^ 0x1BD11BDAu;
  x0 += k0; x1 += k1;
#define TF_R(r) { x0 += x1; x1 = (x1 << (r)) | (x1 >> (32 - (r))); x1 ^= x0; }
  TF_R(13) TF_R(15) TF_R(26) TF_R(6)
  x0 += k1; x1 += ks2 + 1u;
  TF_R(17) TF_R(29) TF_R(16) TF_R(24)
  x0 += ks2; x1 += k0 + 2u;
  TF_R(13) TF_R(15) TF_R(26) TF_R(6)
  x0 += k0; x1 += k1 + 3u;
  TF_R(17) TF_R(29) TF_R(16) TF_R(24)
  x0 += k1; x1 += ks2 + 4u;
  TF_R(13) TF_R(15) TF_R(26) TF_R(6)
  x0 += ks2; x1 += k0 + 5u;
#undef TF_R
  o0 = x0; o1 = x1;
}

__device__ __forceinline__ float mask_from_bits(uint32_t bits) {
  float f = __uint_as_float((bits >> 9) | 0x3f800000u) - 1.0f;
  return (f < 0.75f) ? (1.0f / 0.75f) : 0.0f;
}

// per-edge dropout mask, exact JAX bitstream
__device__ __forceinline__ float edge_mask(int e, uint32_t k0, uint32_t k1) {
  uint32_t x0 = (e < HALF_NNZ) ? (uint32_t)e : (uint32_t)(e - HALF_NNZ);
  uint32_t o0, o1;
  tf2x32(k0, k1, x0, x0 + HALF_NNZ, o0, o1);
  return mask_from_bits((e < HALF_NNZ) ? o0 : o1);
}

// ---------------- CSR/CSC build ----------------
__global__ __launch_bounds__(256) void k_hist(const int* __restrict__ rows,
                                              const int* __restrict__ cols,
                                              int* __restrict__ cnt_r,
                                              int* __restrict__ cnt_c) {
  int e = blockIdx.x * 256 + threadIdx.x;
  if (e < NNZ) {
    atomicAdd(&cnt_r[rows[e]], 1);
    atomicAdd(&cnt_c[cols[e]], 1);
  }
}

// phase 1: per-block sums
__global__ __launch_bounds__(256) void k_bsum(const int* __restrict__ cnt, int n,
                                              int* __restrict__ bsum) {
  int base = blockIdx.x * SC_E + threadIdx.x * 8;
  int s = 0;
#pragma unroll
  for (int j = 0; j < 8; ++j) { int i = base + j; if (i < n) s += cnt[i]; }
  for (int off = 32; off; off >>= 1) s += __shfl_down(s, off);
  __shared__ int ws[4];
  if ((threadIdx.x & 63) == 0) ws[threadIdx.x >> 6] = s;
  __syncthreads();
  if (threadIdx.x == 0) bsum[blockIdx.x] = ws[0] + ws[1] + ws[2] + ws[3];
}

// phase 2: one wave scans <=64 block sums
__global__ __launch_bounds__(64) void k_bscan(const int* __restrict__ bsum, int nb,
                                              int* __restrict__ boff,
                                              int* __restrict__ total_dst) {
  int lane = threadIdx.x;
  int v = (lane < nb) ? bsum[lane] : 0;
  int incl = v;
  for (int off = 1; off < 64; off <<= 1) {
    int t = __shfl_up(incl, off);
    if (lane >= off) incl += t;
  }
  if (lane < nb) boff[lane] = incl - v;
  if (lane == 63) *total_dst = incl;
}

// phase 3: per-block exclusive scan; writes ptr[i] and cursor[i] (may alias cnt)
__global__ __launch_bounds__(256) void k_scan3(const int* cnt, int n,
                                               const int* __restrict__ boff,
                                               int* __restrict__ ptr, int* cursor) {
  int base = blockIdx.x * SC_E + threadIdx.x * 8;
  int c[8]; int s = 0;
#pragma unroll
  for (int j = 0; j < 8; ++j) { int i = base + j; c[j] = (i < n) ? cnt[i] : 0; s += c[j]; }
  int lane = threadIdx.x & 63, wid = threadIdx.x >> 6;
  int incl = s;
  for (int off = 1; off < 64; off <<= 1) {
    int t = __shfl_up(incl, off);
    if (lane >= off) incl += t;
  }
  __shared__ int wsum[4];
  if (lane == 63) wsum[wid] = incl;
  __syncthreads();
  int wpre = 0;
  for (int k = 0; k < wid; ++k) wpre += wsum[k];
  int run = boff[blockIdx.x] + wpre + (incl - s);
#pragma unroll
  for (int j = 0; j < 8; ++j) {
    int i = base + j;
    if (i < n) { ptr[i] = run; cursor[i] = run; run += c[j]; }
  }
}

// scatter: edge ids only (minimum scattered payload)
__global__ __launch_bounds__(256) void k_scatter(const int* __restrict__ rows,
                                                 const int* __restrict__ cols,
                                                 int* __restrict__ cur_r,
                                                 int* __restrict__ cur_c,
                                                 int* __restrict__ perm_r,
                                                 int* __restrict__ perm_c) {
  int e = blockIdx.x * 256 + threadIdx.x;
  if (e < NNZ) {
    int pr = atomicAdd(&cur_r[rows[e]], 1); perm_r[pr] = e;
    int pc = atomicAdd(&cur_c[cols[e]], 1); perm_c[pc] = e;
  }
}

// ---------------- f32 -> bf16 table convert ----------------
__global__ __launch_bounds__(256) void k_tobf(const float* __restrict__ X,
                                              bf16* __restrict__ out, int nelem) {
  int i = blockIdx.x * 256 + threadIdx.x;
  if (i < nelem) out[i] = __float2bfloat16(X[i]);
}

// ---------------- layer-0 SpMM (fused dropout): Z = dropA @ X ----------------
// writes Z as f32 (for wred/sE) and bf16 (gather table for layer 1)
__global__ __launch_bounds__(256) void k_spmm0(const int* __restrict__ ptr,
                                               const int* __restrict__ perm,
                                               const int* __restrict__ gidx,
                                               const float* __restrict__ adj_vals,
                                               const bf16* __restrict__ Xbf,
                                               float* __restrict__ Zf,
                                               bf16* __restrict__ Zbf, int nrows,
                                               uint32_t k0, uint32_t k1) {
  int w = (blockIdx.x * 256 + threadIdx.x) >> 6;
  int lane = threadIdx.x & 63;
  if (w >= nrows) return;
  int beg = ptr[w], end = ptr[w + 1];
  float acc = 0.f;
  for (int kb = beg; kb < end; kb += 64) {
    int cnt = min(64, end - kb);
    float v = 0.f; int c = 0;
    if (lane < cnt) {
      int e = perm[kb + lane];
      v = adj_vals[e] * edge_mask(e, k0, k1);
      c = gidx[e];
    }
    for (int j = 0; j < cnt; ++j) {
      float vj = __shfl(v, j);
      int   cj = __shfl(c, j);
      acc += vj * __bfloat162float(Xbf[(size_t)cj * DIM + lane]);
    }
  }
  Zf[(size_t)w * DIM + lane] = acc;
  Zbf[(size_t)w * DIM + lane] = __float2bfloat16(acc);
}

// ---------------- layer-1 SpMM fused with sE: sE = E0 + Z1 + dropA @ X ----------------
__global__ __launch_bounds__(256) void k_spmm1(const int* __restrict__ ptr,
                                               const int* __restrict__ perm,
                                               const int* __restrict__ gidx,
                                               const float* __restrict__ adj_vals,
                                               const bf16* __restrict__ Xbf,
                                               const float* __restrict__ E0,
                                               const float* __restrict__ Z1f,
                                               float* __restrict__ sEf,
                                               bf16* __restrict__ sEbf, int nrows,
                                               uint32_t k0, uint32_t k1) {
  int w = (blockIdx.x * 256 + threadIdx.x) >> 6;
  int lane = threadIdx.x & 63;
  if (w >= nrows) return;
  int beg = ptr[w], end = ptr[w + 1];
  float acc = 0.f;
  for (int kb = beg; kb < end; kb += 64) {
    int cnt = min(64, end - kb);
    float v = 0.f; int c = 0;
    if (lane < cnt) {
      int e = perm[kb + lane];
      v = adj_vals[e] * edge_mask(e, k0, k1);
      c = gidx[e];
    }
    for (int j = 0; j < cnt; ++j) {
      float vj = __shfl(v, j);
      int   cj = __shfl(c, j);
      acc += vj * __bfloat162float(Xbf[(size_t)cj * DIM + lane]);
    }
  }
  size_t o = (size_t)w * DIM + lane;
  float s = E0[o] + Z1f[o] + acc;
  sEf[o] = s;
  sEbf[o] = __float2bfloat16(s);
}

// ---------------- W += Vt(Q x n) @ X(n x 64) ----------------
__global__ __launch_bounds__(256) void k_wred(const float* __restrict__ Vt,
                                              const float* __restrict__ X,
                                              float* __restrict__ W, int n) {
  int lane = threadIdx.x & 63;
  int w = (blockIdx.x * 256 + threadIdx.x) >> 6;
  int nw = (gridDim.x * 256) >> 6;
  float acc[QDIM] = {0.f, 0.f, 0.f, 0.f, 0.f};
  for (int i = w; i < n; i += nw) {
    float x = X[(size_t)i * DIM + lane];
#pragma unroll
    for (int q = 0; q < QDIM; ++q) acc[q] += Vt[(size_t)q * n + i] * x;
  }
#pragma unroll
  for (int q = 0; q < QDIM; ++q) atomicAdd(&W[q * DIM + lane], acc[q]);
}

// ---------------- batch-row prep ----------------
__global__ __launch_bounds__(256) void k_prep(const int* __restrict__ uids,
                                              const int* __restrict__ pos,
                                              const int* __restrict__ neg,
                                              const float* __restrict__ Eu0,
                                              const float* __restrict__ Ei0,
                                              const float* __restrict__ umuls,
                                              const float* __restrict__ vmuls,
                                              const float* __restrict__ sEuf,
                                              const float* __restrict__ sEif,
                                              const float* __restrict__ Wu,
                                              const float* __restrict__ Wi,
                                              float* __restrict__ gu, float* __restrict__ seu,
                                              float* __restrict__ gi, float* __restrict__ sei,
                                              bf16* __restrict__ Gbf) {
  int row = (blockIdx.x * 256 + threadIdx.x) >> 6;
  int lane = threadIdx.x & 63;
  if (row >= 3 * BATCH) return;
  if (row < BATCH) {
    int u = uids[row];
    size_t base = (size_t)u * DIM + lane;
    float g = Eu0[base];
#pragma unroll
    for (int q = 0; q < QDIM; ++q) g += umuls[u * QDIM + q] * Wu[q * DIM + lane];
    gu[row * DIM + lane] = g;
    Gbf[row * DIM + lane] = __float2bfloat16(g);
    seu[row * DIM + lane] = sEuf[base];
  } else {
    int r = row - BATCH;
    int it = (r < BATCH) ? pos[r] : neg[r - BATCH];
    size_t base = (size_t)it * DIM + lane;
    float g = Ei0[base];
#pragma unroll
    for (int q = 0; q < QDIM; ++q) g += vmuls[it * QDIM + q] * Wi[q * DIM + lane];
    gi[r * DIM + lane] = g;
    Gbf[row * DIM + lane] = __float2bfloat16(g);
    sei[r * DIM + lane] = sEif[base];
  }
}

// ---------------- InfoNCE denominator: 64 rows/wave, 256 rows/block ----------------
__global__ __launch_bounds__(256) void k_negsum(const bf16* __restrict__ G,
                                                const bf16* __restrict__ SE,
                                                float* __restrict__ S,
                                                int n, int n_bblk, int uch) {
  int bblk = blockIdx.x % n_bblk;
  int uc = blockIdx.x / n_bblk;
  int wid = threadIdx.x >> 6;
  int lane = threadIdx.x & 63;
  int b0 = bblk * 256 + wid * 64;
  int fr = lane & 15, fq = lane >> 4;

  bf16x8 a0[4], a1[4];
#pragma unroll
  for (int t = 0; t < 4; ++t) {
    a0[t] = *(const bf16x8*)(G + (size_t)(b0 + t * 16 + fr) * DIM + fq * 8);
    a1[t] = *(const bf16x8*)(G + (size_t)(b0 + t * 16 + fr) * DIM + 32 + fq * 8);
  }

  int tiles = n / 16;
  int per = ((tiles + uch - 1) / uch) * 16;
  int u_lo = uc * per;
  int u_hi = min(n, u_lo + per);

  float racc[16];
#pragma unroll
  for (int j = 0; j < 16; ++j) racc[j] = 0.f;
  const float invT = 5.0f;   // 1/0.2
  for (int u0 = u_lo; u0 < u_hi; u0 += 16) {
    bf16x8 bfr0 = *(const bf16x8*)(SE + (size_t)(u0 + fr) * DIM + fq * 8);
    bf16x8 bfr1 = *(const bf16x8*)(SE + (size_t)(u0 + fr) * DIM + 32 + fq * 8);
#pragma unroll
    for (int t = 0; t < 4; ++t) {
      f32x4 c = {0.f, 0.f, 0.f, 0.f};
      c = __builtin_amdgcn_mfma_f32_16x16x32_bf16(a0[t], bfr0, c, 0, 0, 0);
      c = __builtin_amdgcn_mfma_f32_16x16x32_bf16(a1[t], bfr1, c, 0, 0, 0);
#pragma unroll
      for (int j = 0; j < 4; ++j) racc[t * 4 + j] += __expf(c[j] * invT);
    }
  }
#pragma unroll
  for (int t = 0; t < 4; ++t) {
#pragma unroll
    for (int j = 0; j < 4; ++j) {
      float v = racc[t * 4 + j];
      v += __shfl_xor(v, 1);
      v += __shfl_xor(v, 2);
      v += __shfl_xor(v, 4);
      v += __shfl_xor(v, 8);
      if (fr == 0) atomicAdd(&S[b0 + t * 16 + fq * 4 + j], v);
    }
  }
}

// ---------------- sum of squares (L2 reg) ----------------
__global__ __launch_bounds__(256) void k_sumsq(const float* __restrict__ X, int n,
                                               float* __restrict__ out) {
  size_t i = (size_t)blockIdx.x * 256 + threadIdx.x;
  size_t stride = (size_t)gridDim.x * 256;
  float s = 0.f;
  for (; i < (size_t)n; i += stride) { float v = X[i]; s += v * v; }
  for (int off = 32; off; off >>= 1) s += __shfl_down(s, off);
  __shared__ float part[4];
  if ((threadIdx.x & 63) == 0) part[threadIdx.x >> 6] = s;
  __syncthreads();
  if (threadIdx.x == 0) atomicAdd(out, part[0] + part[1] + part[2] + part[3]);
}

// ---------------- final scalar assembly ----------------
__global__ __launch_bounds__(256) void k_final(const float* __restrict__ Su,
                                               const float* __restrict__ Si,
                                               const float* __restrict__ gu,
                                               const float* __restrict__ seu,
                                               const float* __restrict__ gi,
                                               const float* __restrict__ sei,
                                               const float* __restrict__ sumsq,
                                               float* __restrict__ out) {
  int t = threadIdx.x;
  float negu = 0.f, negi = 0.f, posu = 0.f, posi = 0.f, bpr = 0.f;
  const float invT = 5.0f;
  for (int b = t; b < BATCH; b += 256) {
    negu += logf(Su[b] + 1e-8f);
    float d = 0.f, dp = 0.f, dn = 0.f;
    for (int q = 0; q < DIM; ++q) {
      float u = seu[b * DIM + q];
      d += gu[b * DIM + q] * u;
      dp += u * sei[b * DIM + q];
      dn += u * sei[(b + BATCH) * DIM + q];
    }
    posu += fminf(fmaxf(d * invT, -5.f), 5.f);
    float diff = dp - dn;
    bpr += fmaxf(-diff, 0.f) + log1pf(expf(-fabsf(diff)));
  }
  for (int b = t; b < 2 * BATCH; b += 256) {
    negi += logf(Si[b] + 1e-8f);
    float d = 0.f;
    for (int q = 0; q < DIM; ++q) d += gi[b * DIM + q] * sei[b * DIM + q];
    posi += fminf(fmaxf(d * invT, -5.f), 5.f);
  }
  __shared__ float red[5][4];
  float vals5[5] = {negu, negi, posu, posi, bpr};
#pragma unroll
  for (int k = 0; k < 5; ++k) {
    float v = vals5[k];
    for (int off = 32; off; off >>= 1) v += __shfl_down(v, off);
    if ((t & 63) == 0) red[k][t >> 6] = v;
  }
  __syncthreads();
  if (t == 0) {
    float nu = red[0][0] + red[0][1] + red[0][2] + red[0][3];
    float ni = red[1][0] + red[1][1] + red[1][2] + red[1][3];
    float pu = red[2][0] + red[2][1] + red[2][2] + red[2][3];
    float pi = red[3][0] + red[3][1] + red[3][2] + red[3][3];
    float bp = red[4][0] + red[4][1] + red[4][2] + red[4][3];
    float neg_score = nu / (float)BATCH + ni / (float)(2 * BATCH);
    float pos_score = pu / (float)BATCH + pi / (float)(2 * BATCH);
    float loss_s = -pos_score + neg_score;
    float loss_r = bp / (float)BATCH;
    float ls = 0.2f * loss_s;
    float reg = 1e-5f * sumsq[0];
    out[0] = loss_r + ls + reg;
    out[1] = loss_r;
    out[2] = ls;
  }
}

extern "C" void kernel_launch(void* const* d_in, const int* in_sizes, int n_in,
                              void* d_out, int out_size, void* d_ws, size_t ws_size,
                              hipStream_t stream) {
  const float* Eu0   = (const float*)d_in[0];
  const float* Ei0   = (const float*)d_in[1];
  const float* umuls = (const float*)d_in[2];
  const float* vmuls = (const float*)d_in[3];
  const float* ut    = (const float*)d_in[4];
  const float* vt    = (const float*)d_in[5];
  const float* adj_vals = (const float*)d_in[6];
  const int* adj_rows = (const int*)d_in[7];
  const int* adj_cols = (const int*)d_in[8];
  const int* uids = (const int*)d_in[9];
  const int* pos  = (const int*)d_in[10];
  const int* neg  = (const int*)d_in[11];
  float* out = (float*)d_out;

  char* w = (char*)d_ws;
  size_t off = 0;
  auto alloc = [&](size_t bytes) -> void* {
    void* p = w + off;
    off = (off + bytes + 255) & ~(size_t)255;
    return p;
  };
  float* Zu1f = (float*)alloc(sizeof(float) * N_USERS * DIM);
  float* Zi1f = (float*)alloc(sizeof(float) * N_ITEMS * DIM);
  bf16* Zu1bf = (bf16*)alloc(sizeof(bf16) * N_USERS * DIM);
  bf16* Zi1bf = (bf16*)alloc(sizeof(bf16) * N_ITEMS * DIM);
  float* sEuf = (float*)alloc(sizeof(float) * N_USERS * DIM);
  float* sEif = (float*)alloc(sizeof(float) * N_ITEMS * DIM);
  bf16* sEubf = (bf16*)alloc(sizeof(bf16) * N_USERS * DIM);
  bf16* sEibf = (bf16*)alloc(sizeof(bf16) * N_ITEMS * DIM);
  bf16* Eu0bf = (bf16*)alloc(sizeof(bf16) * N_USERS * DIM);
  bf16* Ei0bf = (bf16*)alloc(sizeof(bf16) * N_ITEMS * DIM);
  int* perm_r = (int*)alloc(sizeof(int) * NNZ);
  int* perm_c = (int*)alloc(sizeof(int) * NNZ);
  int* row_ptr = (int*)alloc(sizeof(int) * (N_USERS + 1));
  int* col_ptr = (int*)alloc(sizeof(int) * (N_ITEMS + 1));
  int* cur_r = (int*)alloc(sizeof(int) * N_USERS);
  int* cur_c = (int*)alloc(sizeof(int) * N_ITEMS);
  int* bsum = (int*)alloc(sizeof(int) * 64);
  int* boff = (int*)alloc(sizeof(int) * 64);
  int* bsum2 = (int*)alloc(sizeof(int) * 64);
  int* boff2 = (int*)alloc(sizeof(int) * 64);
  float* Wu = (float*)alloc(sizeof(float) * QDIM * DIM);
  float* Wi = (float*)alloc(sizeof(float) * QDIM * DIM);
  float* gu  = (float*)alloc(sizeof(float) * BATCH * DIM);
  float* gi  = (float*)alloc(sizeof(float) * 2 * BATCH * DIM);
  float* seu = (float*)alloc(sizeof(float) * BATCH * DIM);
  float* sei = (float*)alloc(sizeof(float) * 2 * BATCH * DIM);
  bf16* Gbf = (bf16*)alloc(sizeof(bf16) * 3 * BATCH * DIM);
  float* Su = (float*)alloc(sizeof(float) * BATCH);
  float* Si = (float*)alloc(sizeof(float) * 2 * BATCH);
  float* scal = (float*)alloc(sizeof(float) * 4);

  // folded dropout keys: fold_in(key(42), idx) for idx = 0..3
  uint32_t mk[4][2];
  for (uint32_t i = 0; i < 4; ++i) tf2x32(0u, 42u, 0u, i, mk[i][0], mk[i][1]);

  const int NB_U = (N_USERS + SC_E - 1) / SC_E;   // 49
  const int NB_I = (N_ITEMS + SC_E - 1) / SC_E;   // 25

  hipMemsetAsync(cur_r, 0, sizeof(int) * N_USERS, stream);
  hipMemsetAsync(cur_c, 0, sizeof(int) * N_ITEMS, stream);
  hipMemsetAsync(Wu, 0, sizeof(float) * QDIM * DIM, stream);
  hipMemsetAsync(Wi, 0, sizeof(float) * QDIM * DIM, stream);
  hipMemsetAsync(Su, 0, sizeof(float) * BATCH, stream);
  hipMemsetAsync(Si, 0, sizeof(float) * 2 * BATCH, stream);
  hipMemsetAsync(scal, 0, sizeof(float) * 4, stream);

  // CSR/CSC build
  k_hist<<<(NNZ + 255) / 256, 256, 0, stream>>>(adj_rows, adj_cols, cur_r, cur_c);
  k_bsum<<<NB_U, 256, 0, stream>>>(cur_r, N_USERS, bsum);
  k_bscan<<<1, 64, 0, stream>>>(bsum, NB_U, boff, row_ptr + N_USERS);
  k_scan3<<<NB_U, 256, 0, stream>>>(cur_r, N_USERS, boff, row_ptr, cur_r);
  k_bsum<<<NB_I, 256, 0, stream>>>(cur_c, N_ITEMS, bsum2);
  k_bscan<<<1, 64, 0, stream>>>(bsum2, NB_I, boff2, col_ptr + N_ITEMS);
  k_scan3<<<NB_I, 256, 0, stream>>>(cur_c, N_ITEMS, boff2, col_ptr, cur_c);
  k_scatter<<<(NNZ + 255) / 256, 256, 0, stream>>>(adj_rows, adj_cols, cur_r, cur_c,
                                                   perm_r, perm_c);

  // bf16 gather tables for E0
  k_tobf<<<(N_USERS * DIM + 255) / 256, 256, 0, stream>>>(Eu0, Eu0bf, N_USERS * DIM);
  k_tobf<<<(N_ITEMS * DIM + 255) / 256, 256, 0, stream>>>(Ei0, Ei0bf, N_ITEMS * DIM);

  // layer 0 (fused dropout in SpMM)
  k_spmm0<<<N_USERS * 64 / 256, 256, 0, stream>>>(row_ptr, perm_r, adj_cols, adj_vals,
                                                  Ei0bf, Zu1f, Zu1bf, N_USERS,
                                                  mk[0][0], mk[0][1]);
  k_spmm0<<<N_ITEMS * 64 / 256, 256, 0, stream>>>(col_ptr, perm_c, adj_rows, adj_vals,
                                                  Eu0bf, Zi1f, Zi1bf, N_ITEMS,
                                                  mk[1][0], mk[1][1]);
  k_wred<<<256, 256, 0, stream>>>(vt, Ei0, Wu, N_ITEMS);
  k_wred<<<256, 256, 0, stream>>>(ut, Eu0, Wi, N_USERS);

  // layer 1 (fused dropout + sE computation)
  k_spmm1<<<N_USERS * 64 / 256, 256, 0, stream>>>(row_ptr, perm_r, adj_cols, adj_vals,
                                                  Zi1bf, Eu0, Zu1f, sEuf, sEubf, N_USERS,
                                                  mk[2][0], mk[2][1]);
  k_spmm1<<<N_ITEMS * 64 / 256, 256, 0, stream>>>(col_ptr, perm_c, adj_rows, adj_vals,
                                                  Zu1bf, Ei0, Zi1f, sEif, sEibf, N_ITEMS,
                                                  mk[3][0], mk[3][1]);
  k_wred<<<256, 256, 0, stream>>>(vt, Zi1f, Wu, N_ITEMS);
  k_wred<<<256, 256, 0, stream>>>(ut, Zu1f, Wi, N_USERS);

  // batch prep
  k_prep<<<(3 * BATCH * 64) / 256, 256, 0, stream>>>(uids, pos, neg, Eu0, Ei0, umuls, vmuls,
                                                     sEuf, sEif, Wu, Wi,
                                                     gu, seu, gi, sei, Gbf);

  // InfoNCE denominators (MFMA, 256 rows/block)
  k_negsum<<<4 * 128, 256, 0, stream>>>(Gbf, sEubf, Su, N_USERS, 4, 128);
  k_negsum<<<8 * 64, 256, 0, stream>>>(Gbf + (size_t)BATCH * DIM, sEibf, Si, N_ITEMS, 8, 64);

  // L2 reg
  k_sumsq<<<2048, 256, 0, stream>>>(Eu0, N_USERS * DIM, scal);
  k_sumsq<<<1024, 256, 0, stream>>>(Ei0, N_ITEMS * DIM, scal);

  // final scalars
  k_final<<<1, 256, 0, stream>>>(Su, Si, gu, seu, gi, sei, scal, out);
}